// Round 10
// baseline (174.455 us; speedup 1.0000x reference)
//
#include <hip/hip_runtime.h>
#include <hip/hip_bf16.h>

#define NN 23
#define BLK 256
#define SPB 16           // samples per block
#define WST 104          // s_feat row stride (bf16 elems)
#define XST 136          // s_xc row stride
#define W1TK 96          // w1t global row stride (k elems, 92 + 4 pad)
#define PWTK 128         // pwt global row stride

typedef __attribute__((ext_vector_type(8))) short bf16x8;
typedef __attribute__((ext_vector_type(4))) float f32x4;

__device__ __forceinline__ unsigned short f2b(float f) {
    union { __hip_bfloat16 h; unsigned short u; } c; c.h = __float2bfloat16(f); return c.u;
}
__device__ __forceinline__ float geluf(float v) {
    return 0.5f * v * (1.0f + erff(v * 0.70710678118654752f));
}

// One-shot weight prep into d_ws: w1t = fc1w^T as bf16 [n=128][k=96, zero-pad 92..95],
// pwt = prew^T as bf16 [t=16][k=128]. Runs every kernel_launch call (ws is re-poisoned).
__global__ __launch_bounds__(256) void prep(const float* __restrict__ fc1w,
                                            const float* __restrict__ prew,
                                            unsigned short* __restrict__ w1t,
                                            unsigned short* __restrict__ pwt) {
    const int tid = blockIdx.x * 256 + threadIdx.x;
    const int NT = gridDim.x * 256;
    for (int i = tid; i < 128 * W1TK; i += NT) {
        const int n = i / W1TK, k = i - n * W1TK;
        w1t[i] = (k < 92) ? f2b(fc1w[k * 128 + n]) : (unsigned short)0;
    }
    for (int j = tid; j < 16 * PWTK; j += NT) {
        const int t = j >> 7, k = j & 127;
        pwt[j] = f2b(prew[k * 16 + t]);
    }
}

// 16 samples/block, 8 blocks/CU. Attention: 8x 32-lane groups, 2 samples each
// (ballot row-mask + lane-local column softmax + row recompute). fc1/pre via
// MFMA 16x16x32 bf16 with B-fragments read straight from global (L2-hot ws).
__global__ __launch_bounds__(BLK, 8) void gat_fused(
    const float* __restrict__ xattr, const int* __restrict__ adj,
    const float* __restrict__ W0,   const float* __restrict__ a0,
    const float* __restrict__ W1,   const float* __restrict__ a1,
    const unsigned short* __restrict__ w1t, const float* __restrict__ fc1b,
    const unsigned short* __restrict__ pwt, const float* __restrict__ preb,
    const float* __restrict__ predw, const float* __restrict__ predb,
    const float* __restrict__ varw,  const float* __restrict__ varb,
    float* __restrict__ outy, float* __restrict__ outv, float* __restrict__ outxc)
{
    __shared__ unsigned short s_feat[SPB * WST]; // feat bf16 [s][k]: 3328 B
    __shared__ unsigned short s_xc[SPB * XST];   // xc bf16 [s][k]:   4352 B
    __shared__ float s_fc1b[128];                // 512 B
    __shared__ float s_aux[64];                  // 256 B -> total 8448 B => 8 blocks/CU

    const int tid = threadIdx.x;

    if (tid < 128) s_fc1b[tid] = fc1b[tid];
    if (tid >= 128 && tid < 144) {
        const int t = tid - 128;
        s_aux[12 + t] = preb[t];
        s_aux[28 + t] = predw[t];
        s_aux[44 + t] = varw[t];
    }
    if (tid == 144) {
        s_aux[0] = W0[0]; s_aux[1] = W0[1];
        s_aux[2] = a0[0]; s_aux[3] = a0[1]; s_aux[4] = a0[2]; s_aux[5] = a0[3];
        s_aux[6] = W1[0]; s_aux[7] = W1[1];
        s_aux[8] = a1[0]; s_aux[9] = a1[1]; s_aux[10] = a1[2]; s_aux[11] = a1[3];
        s_aux[60] = predb[0]; s_aux[61] = varb[0];
    }
    if (tid >= 160 && tid < 192) {               // zero s_feat pad cols 92..95
        const int r = (tid - 160) >> 1, u = tid & 1;
        *(unsigned*)&s_feat[r * WST + 92 + 2 * u] = 0u;
    }
    __syncthreads();

    const int group = tid >> 5;
    const int l     = tid & 31;

    // ---- attention: 2 samples per 32-lane group ----
    #pragma unroll 1
    for (int rnd = 0; rnd < 2; ++rnd) {
        const int sl = group * 2 + rnd;              // local sample 0..15
        const int s  = blockIdx.x * SPB + sl;

        float xl = 0.0f;
        if (l < NN) xl = xattr[s * NN + l];
        float xv[NN];
        #pragma unroll
        for (int i = 0; i < NN; ++i) xv[i] = __shfl(xl, i, 32);

        unsigned cm = 0u;
        if (l < NN) {
            const int* ar = adj + (size_t)s * (NN * NN);
            #pragma unroll
            for (int i = 0; i < NN; ++i) cm |= (ar[i * NN + l] != 0) ? (1u << i) : 0u;
        }
        unsigned rm = 0u;
        #pragma unroll
        for (int i = 0; i < NN; ++i) {
            unsigned long long bal = __ballot((cm >> i) & 1u);
            unsigned half = (unsigned)(bal >> (tid & 32));
            rm = (l == i) ? half : rm;
        }
        unsigned em;
        {
            unsigned long long bal = __ballot(cm == 0u);
            em = ((unsigned)(bal >> (tid & 32))) & 0x7FFFFFu;
        }
        float sbase = 0.0f;
        #pragma unroll
        for (int j = 0; j < NN; ++j) sbase += ((em >> j) & 1u) ? xv[j] : 0.0f;
        sbase *= (1.0f / 23.0f);   // jax softmax of all -1e20 -> uniform 1/23

        float fmine[4];
        #pragma unroll
        for (int h = 0; h < 2; ++h) {
            const float w0 = s_aux[h * 6 + 0], w1 = s_aux[h * 6 + 1];
            const float c1 = w0 * s_aux[h * 6 + 2] + w1 * s_aux[h * 6 + 3];
            const float c2 = w0 * s_aux[h * 6 + 4] + w1 * s_aux[h * 6 + 5];

            // column pass: dcol = sum_i masked exp(lrelu(c1*x_i + c2*x_l))  (lane-local)
            const float f2l = xl * c2;
            float dcol = 0.0f;
            #pragma unroll
            for (int i = 0; i < NN; ++i) {
                float e = fmaf(xv[i], c1, f2l);
                e = fmaxf(e, 0.2f * e);
                float t = ((cm >> i) & 1u) ? 1.0f : 0.0f;
                dcol = fmaf(__expf(e), t, dcol);
            }
            const float scl = (cm == 0u) ? 0.0f : __fdividef(xl, dcol);

            float sclv[NN];
            #pragma unroll
            for (int j = 0; j < NN; ++j) sclv[j] = __shfl(scl, j, 32);

            // row pass: s_l = sbase + sum_j masked exp(lrelu(c1*x_l + c2*x_j)) * scl_j
            const float f1 = xl * c1;
            float sown = sbase;
            #pragma unroll
            for (int j = 0; j < NN; ++j) {
                float e = fmaf(xv[j], c2, f1);
                e = fmaxf(e, 0.2f * e);
                float t = ((rm >> j) & 1u) ? sclv[j] : 0.0f;
                sown = fmaf(__expf(e), t, sown);
            }
            fmine[h * 2 + 0] = geluf(w0 * sown);
            fmine[h * 2 + 1] = geluf(w1 * sown);
        }

        if (l < NN) {
            unsigned lo = (unsigned)f2b(fmine[0]) | ((unsigned)f2b(fmine[1]) << 16);
            unsigned hi = (unsigned)f2b(fmine[2]) | ((unsigned)f2b(fmine[3]) << 16);
            *(uint2*)&s_feat[sl * WST + 4 * l] = make_uint2(lo, hi);
        }
    }
    __syncthreads();

    // ---- fc1 via MFMA: wave w owns output cols [32w, 32w+32); B from global ----
    {
        const int wave = tid >> 6;
        const int lane = tid & 63;
        const int q    = lane >> 4;      // k-chunk / C row-group
        const int c16  = lane & 15;

        f32x4 acc0 = {0.f, 0.f, 0.f, 0.f};
        f32x4 acc1 = {0.f, 0.f, 0.f, 0.f};
        const int n0 = 32 * wave + c16;
        const int n1 = n0 + 16;
        #pragma unroll
        for (int t = 0; t < 3; ++t) {
            const bf16x8 a  = *(const bf16x8*)&s_feat[c16 * WST + 32 * t + 8 * q];
            const bf16x8 b0 = *(const bf16x8*)&w1t[n0 * W1TK + 32 * t + 8 * q];
            const bf16x8 b1 = *(const bf16x8*)&w1t[n1 * W1TK + 32 * t + 8 * q];
            acc0 = __builtin_amdgcn_mfma_f32_16x16x32_bf16(a, b0, acc0, 0, 0, 0);
            acc1 = __builtin_amdgcn_mfma_f32_16x16x32_bf16(a, b1, acc1, 0, 0, 0);
        }
        const float bia0 = s_fc1b[n0], bia1 = s_fc1b[n1];
        const size_t gbase = (size_t)blockIdx.x * SPB * 128;
        #pragma unroll
        for (int r = 0; r < 4; ++r) {
            const int srow = 4 * q + r;
            const float v0 = fmaxf(acc0[r] + bia0, 0.0f);
            const float v1 = fmaxf(acc1[r] + bia1, 0.0f);
            outxc[gbase + (size_t)srow * 128 + n0] = v0;
            outxc[gbase + (size_t)srow * 128 + n1] = v1;
            s_xc[srow * XST + n0] = f2b(v0);
            s_xc[srow * XST + n1] = f2b(v1);
        }
    }
    __syncthreads();

    // ---- pre via MFMA (wave 0, B from global) + epilogue ----
    if (tid < 64) {
        const int q   = tid >> 4;
        const int c16 = tid & 15;   // pre-output index
        f32x4 acc = {0.f, 0.f, 0.f, 0.f};
        #pragma unroll
        for (int t = 0; t < 4; ++t) {
            const bf16x8 a = *(const bf16x8*)&s_xc[c16 * XST + 32 * t + 8 * q];
            const bf16x8 b = *(const bf16x8*)&pwt[c16 * PWTK + 32 * t + 8 * q];
            acc = __builtin_amdgcn_mfma_f32_16x16x32_bf16(a, b, acc, 0, 0, 0);
        }
        const float pb = s_aux[12 + c16], pw = s_aux[28 + c16], vw = s_aux[44 + c16];
        float yp[4], vp[4];
        #pragma unroll
        for (int r = 0; r < 4; ++r) {
            const float g = geluf(acc[r] + pb);
            yp[r] = g * pw;
            vp[r] = g * vw;
        }
        #pragma unroll
        for (int m = 1; m < 16; m <<= 1) {
            #pragma unroll
            for (int r = 0; r < 4; ++r) {
                yp[r] += __shfl_xor(yp[r], m, 64);
                vp[r] += __shfl_xor(vp[r], m, 64);
            }
        }
        if (c16 == 0) {
            const int sb = blockIdx.x * SPB + 4 * q;
            #pragma unroll
            for (int r = 0; r < 4; ++r) {
                outy[sb + r] = fmaxf(yp[r] + s_aux[60], 0.0f);
                outv[sb + r] = vp[r] + s_aux[61];
            }
        }
    }
}

extern "C" void kernel_launch(void* const* d_in, const int* in_sizes, int n_in,
                              void* d_out, int out_size, void* d_ws, size_t ws_size,
                              hipStream_t stream) {
    const float* xattr = (const float*)d_in[0];
    const int*   adjp  = (const int*)d_in[1];

    const int B = in_sizes[0] / NN;   // 16384
    float* o = (float*)d_out;
    float* outy  = o;
    float* outv  = o + B;
    float* outxc = o + 2 * (size_t)B;

    unsigned short* w1t = (unsigned short*)d_ws;                  // 128*96*2 = 24576 B
    unsigned short* pwt = (unsigned short*)((char*)d_ws + 24576); // 16*128*2 =  4096 B

    prep<<<dim3(16), dim3(256), 0, stream>>>(
        (const float*)d_in[6], (const float*)d_in[8], w1t, pwt);

    gat_fused<<<dim3(B / SPB), dim3(BLK), 0, stream>>>(
        xattr, adjp,
        (const float*)d_in[2], (const float*)d_in[3],
        (const float*)d_in[4], (const float*)d_in[5],
        w1t, (const float*)d_in[7],
        pwt, (const float*)d_in[9],
        (const float*)d_in[10], (const float*)d_in[11],
        (const float*)d_in[12], (const float*)d_in[13],
        outy, outv, outxc);
}

// Round 11
// 135.787 us; speedup vs baseline: 1.2848x; 1.2848x over previous
//
#include <hip/hip_runtime.h>
#include <hip/hip_bf16.h>

#define NN 23
#define BLK 512
#define SPB 16           // samples per block: one per 32-lane group
#define WST 104          // s_feat row stride (bf16 elems)
#define XST 136          // s_xc row stride (bf16 elems)
#define FST 132          // s_xcf row stride (f32 elems, 16B-aligned)
#define W1TK 96          // w1t global row stride (k elems, 92 + 4 pad)
#define PWTK 128         // pwt global row stride

typedef __attribute__((ext_vector_type(8))) short bf16x8;
typedef __attribute__((ext_vector_type(4))) float f32x4;

__device__ __forceinline__ unsigned short f2b(float f) {
    union { __hip_bfloat16 h; unsigned short u; } c; c.h = __float2bfloat16(f); return c.u;
}
__device__ __forceinline__ float geluf(float v) {
    return 0.5f * v * (1.0f + erff(v * 0.70710678118654752f));
}

// One-shot weight prep into d_ws: w1t = fc1w^T bf16 [n=128][k=96, pad 92..95=0],
// pwt = prew^T bf16 [t=16][k=128]. Runs every call (ws is re-poisoned).
__global__ __launch_bounds__(256) void prep(const float* __restrict__ fc1w,
                                            const float* __restrict__ prew,
                                            unsigned short* __restrict__ w1t,
                                            unsigned short* __restrict__ pwt) {
    const int tid = blockIdx.x * 256 + threadIdx.x;
    const int NT = gridDim.x * 256;
    for (int i = tid; i < 128 * W1TK; i += NT) {
        const int n = i / W1TK, k = i - n * W1TK;
        w1t[i] = (k < 92) ? f2b(fc1w[k * 128 + n]) : (unsigned short)0;
    }
    for (int j = tid; j < 16 * PWTK; j += NT) {
        const int t = j >> 7, k = j & 127;
        pwt[j] = f2b(prew[k * 16 + t]);
    }
}

// 512 threads / 16 samples per block (1 sample per 32-lane group) -> 8192 waves
// total = 32 waves/CU capacity. Attention: ballot row-mask + lane-local column
// softmax + row recompute (inline shfl, no big arrays -> fits 64 VGPR for
// 8 waves/SIMD). fc1: MFMA 16x16x32, wave w owns 16 cols, B from L2-hot ws.
// xc stored via f32 LDS tile -> one linear float4 per thread (no partial-line RMW).
__global__ __launch_bounds__(BLK, 8) void gat_fused(
    const float* __restrict__ xattr, const int* __restrict__ adj,
    const float* __restrict__ W0,   const float* __restrict__ a0,
    const float* __restrict__ W1,   const float* __restrict__ a1,
    const unsigned short* __restrict__ w1t, const float* __restrict__ fc1b,
    const unsigned short* __restrict__ pwt, const float* __restrict__ preb,
    const float* __restrict__ predw, const float* __restrict__ predb,
    const float* __restrict__ varw,  const float* __restrict__ varb,
    float* __restrict__ outy, float* __restrict__ outv, float* __restrict__ outxc)
{
    __shared__ unsigned short s_feat[SPB * WST]; // 3328 B
    __shared__ unsigned short s_xc[SPB * XST];   // 4352 B
    __shared__ float s_xcf[SPB * FST];           // 8448 B
    __shared__ float s_fc1b[128];                // 512 B
    __shared__ float s_aux[64];                  // 256 B  -> ~16.9 KB total

    const int tid = threadIdx.x;

    if (tid < 128) s_fc1b[tid] = fc1b[tid];
    else if (tid < 144) {
        const int t = tid - 128;
        s_aux[12 + t] = preb[t];
        s_aux[28 + t] = predw[t];
        s_aux[44 + t] = varw[t];
    }
    else if (tid == 144) {
        s_aux[0] = W0[0]; s_aux[1] = W0[1];
        s_aux[2] = a0[0]; s_aux[3] = a0[1]; s_aux[4] = a0[2]; s_aux[5] = a0[3];
        s_aux[6] = W1[0]; s_aux[7] = W1[1];
        s_aux[8] = a1[0]; s_aux[9] = a1[1]; s_aux[10] = a1[2]; s_aux[11] = a1[3];
        s_aux[60] = predb[0]; s_aux[61] = varb[0];
    }
    else if (tid >= 160 && tid < 192) {          // zero s_feat pad cols 92..95
        const int r = (tid - 160) >> 1, u = tid & 1;
        *(unsigned*)&s_feat[r * WST + 92 + 2 * u] = 0u;
    }
    __syncthreads();

    const int group = tid >> 5;                  // 0..15 = local sample
    const int l     = tid & 31;
    const int s     = blockIdx.x * SPB + group;

    // ---- attention (1 sample per group) ----
    {
        float xl = 0.0f;
        if (l < NN) xl = xattr[s * NN + l];
        float xv[NN];
        #pragma unroll
        for (int i = 0; i < NN; ++i) xv[i] = __shfl(xl, i, 32);

        unsigned cm = 0u;
        if (l < NN) {
            const int* ar = adj + (size_t)s * (NN * NN);
            #pragma unroll
            for (int i = 0; i < NN; ++i) cm |= (ar[i * NN + l] != 0) ? (1u << i) : 0u;
        }
        unsigned rm = 0u;
        #pragma unroll
        for (int i = 0; i < NN; ++i) {
            unsigned long long bal = __ballot((cm >> i) & 1u);
            unsigned half = (unsigned)(bal >> (tid & 32));
            rm = (l == i) ? half : rm;
        }
        unsigned em;
        {
            unsigned long long bal = __ballot(cm == 0u);
            em = ((unsigned)(bal >> (tid & 32))) & 0x7FFFFFu;
        }
        float sbase = 0.0f;
        #pragma unroll
        for (int j = 0; j < NN; ++j) sbase += ((em >> j) & 1u) ? xv[j] : 0.0f;
        sbase *= (1.0f / 23.0f);   // jax softmax of all -1e20 -> uniform 1/23

        float fmine[4];
        #pragma unroll
        for (int h = 0; h < 2; ++h) {
            const float w0 = s_aux[h * 6 + 0], w1 = s_aux[h * 6 + 1];
            const float c1 = w0 * s_aux[h * 6 + 2] + w1 * s_aux[h * 6 + 3];
            const float c2 = w0 * s_aux[h * 6 + 4] + w1 * s_aux[h * 6 + 5];

            // column pass: dcol = sum_i masked exp(lrelu(c1*x_i + c2*x_l)) (lane-local)
            const float f2l = xl * c2;
            float dcol = 0.0f;
            #pragma unroll
            for (int i = 0; i < NN; ++i) {
                float e = fmaf(xv[i], c1, f2l);
                e = fmaxf(e, 0.2f * e);
                float t = ((cm >> i) & 1u) ? 1.0f : 0.0f;
                dcol = fmaf(__expf(e), t, dcol);
            }
            const float scl = (cm == 0u) ? 0.0f : __fdividef(xl, dcol);

            // row pass with inline broadcast (no sclv array -> fewer live VGPRs)
            const float f1 = xl * c1;
            float sown = sbase;
            #pragma unroll
            for (int j = 0; j < NN; ++j) {
                const float sj = __shfl(scl, j, 32);
                float e = fmaf(xv[j], c2, f1);
                e = fmaxf(e, 0.2f * e);
                sown = fmaf(__expf(e), ((rm >> j) & 1u) ? sj : 0.0f, sown);
            }
            fmine[h * 2 + 0] = geluf(w0 * sown);
            fmine[h * 2 + 1] = geluf(w1 * sown);
        }

        if (l < NN) {
            unsigned lo = (unsigned)f2b(fmine[0]) | ((unsigned)f2b(fmine[1]) << 16);
            unsigned hi = (unsigned)f2b(fmine[2]) | ((unsigned)f2b(fmine[3]) << 16);
            *(uint2*)&s_feat[group * WST + 4 * l] = make_uint2(lo, hi);
        }
    }
    __syncthreads();

    // ---- fc1 via MFMA: wave w (0..7) owns output cols [16w, 16w+16) ----
    {
        const int wave = tid >> 6;
        const int lane = tid & 63;
        const int q    = lane >> 4;      // k-chunk / C row-group
        const int c16  = lane & 15;
        const int n0   = 16 * wave + c16;

        f32x4 acc = {0.f, 0.f, 0.f, 0.f};
        #pragma unroll
        for (int t = 0; t < 3; ++t) {
            const bf16x8 a = *(const bf16x8*)&s_feat[c16 * WST + 32 * t + 8 * q];
            const bf16x8 b = *(const bf16x8*)&w1t[n0 * W1TK + 32 * t + 8 * q];
            acc = __builtin_amdgcn_mfma_f32_16x16x32_bf16(a, b, acc, 0, 0, 0);
        }
        const float bia = s_fc1b[n0];
        #pragma unroll
        for (int r = 0; r < 4; ++r) {
            const int srow = 4 * q + r;
            const float v = fmaxf(acc[r] + bia, 0.0f);
            s_xcf[srow * FST + n0] = v;
            s_xc[srow * XST + n0]  = f2b(v);
        }
    }
    __syncthreads();

    // ---- coalesced xc store: 512 threads x one linear float4 (8 KB/block) ----
    {
        const size_t gbase = (size_t)blockIdx.x * SPB * 128;
        const int row = tid >> 5, c = (tid & 31) * 4;
        *(float4*)&outxc[gbase + 4 * (size_t)tid] = *(const float4*)&s_xcf[row * FST + c];
    }

    // ---- pre via MFMA (wave 0, B from global) + epilogue ----
    if (tid < 64) {
        const int q   = tid >> 4;
        const int c16 = tid & 15;   // pre-output index
        f32x4 acc = {0.f, 0.f, 0.f, 0.f};
        #pragma unroll
        for (int t = 0; t < 4; ++t) {
            const bf16x8 a = *(const bf16x8*)&s_xc[c16 * XST + 32 * t + 8 * q];
            const bf16x8 b = *(const bf16x8*)&pwt[c16 * PWTK + 32 * t + 8 * q];
            acc = __builtin_amdgcn_mfma_f32_16x16x32_bf16(a, b, acc, 0, 0, 0);
        }
        const float pb = s_aux[12 + c16], pw = s_aux[28 + c16], vw = s_aux[44 + c16];
        float yp[4], vp[4];
        #pragma unroll
        for (int r = 0; r < 4; ++r) {
            const float g = geluf(acc[r] + pb);
            yp[r] = g * pw;
            vp[r] = g * vw;
        }
        #pragma unroll
        for (int m = 1; m < 16; m <<= 1) {
            #pragma unroll
            for (int r = 0; r < 4; ++r) {
                yp[r] += __shfl_xor(yp[r], m, 64);
                vp[r] += __shfl_xor(vp[r], m, 64);
            }
        }
        if (c16 == 0) {
            const int sb = blockIdx.x * SPB + 4 * q;
            #pragma unroll
            for (int r = 0; r < 4; ++r) {
                outy[sb + r] = fmaxf(yp[r] + s_aux[60], 0.0f);
                outv[sb + r] = vp[r] + s_aux[61];
            }
        }
    }
}

extern "C" void kernel_launch(void* const* d_in, const int* in_sizes, int n_in,
                              void* d_out, int out_size, void* d_ws, size_t ws_size,
                              hipStream_t stream) {
    const float* xattr = (const float*)d_in[0];
    const int*   adjp  = (const int*)d_in[1];

    const int B = in_sizes[0] / NN;   // 16384
    float* o = (float*)d_out;
    float* outy  = o;
    float* outv  = o + B;
    float* outxc = o + 2 * (size_t)B;

    unsigned short* w1t = (unsigned short*)d_ws;                  // 128*96*2 = 24576 B
    unsigned short* pwt = (unsigned short*)((char*)d_ws + 24576); // 16*128*2 =  4096 B

    prep<<<dim3(16), dim3(256), 0, stream>>>(
        (const float*)d_in[6], (const float*)d_in[8], w1t, pwt);

    gat_fused<<<dim3(B / SPB), dim3(BLK), 0, stream>>>(
        xattr, adjp,
        (const float*)d_in[2], (const float*)d_in[3],
        (const float*)d_in[4], (const float*)d_in[5],
        w1t, (const float*)d_in[7],
        pwt, (const float*)d_in[9],
        (const float*)d_in[10], (const float*)d_in[11],
        (const float*)d_in[12], (const float*)d_in[13],
        outy, outv, outxc);
}

// Round 12
// 120.499 us; speedup vs baseline: 1.4478x; 1.1269x over previous
//
#include <hip/hip_runtime.h>
#include <hip/hip_bf16.h>

#define NN 23
#define BLK 512
#define SPB 16           // samples per block: one per 32-lane group
#define WST 104          // s_feat row stride (bf16 elems)
#define XST 136          // s_xc row stride (bf16 elems)
#define FST 132          // s_xcf row stride (f32 elems, 16B-aligned)
#define W1TK 96          // w1t global row stride (k elems, 92 + 4 pad)
#define PWTK 128         // pwt global row stride

typedef __attribute__((ext_vector_type(8))) short bf16x8;
typedef __attribute__((ext_vector_type(4))) float f32x4;

__device__ __forceinline__ unsigned short f2b(float f) {
    union { __hip_bfloat16 h; unsigned short u; } c; c.h = __float2bfloat16(f); return c.u;
}
__device__ __forceinline__ float geluf(float v) {
    return 0.5f * v * (1.0f + erff(v * 0.70710678118654752f));
}

// One-shot weight prep into d_ws: w1t = fc1w^T bf16 [n=128][k=96, pad 92..95=0],
// pwt = prew^T bf16 [t=16][k=128]. Runs every call (ws is re-poisoned).
__global__ __launch_bounds__(256) void prep(const float* __restrict__ fc1w,
                                            const float* __restrict__ prew,
                                            unsigned short* __restrict__ w1t,
                                            unsigned short* __restrict__ pwt) {
    const int tid = blockIdx.x * 256 + threadIdx.x;
    const int NT = gridDim.x * 256;
    for (int i = tid; i < 128 * W1TK; i += NT) {
        const int n = i / W1TK, k = i - n * W1TK;
        w1t[i] = (k < 92) ? f2b(fc1w[k * 128 + n]) : (unsigned short)0;
    }
    for (int j = tid; j < 16 * PWTK; j += NT) {
        const int t = j >> 7, k = j & 127;
        pwt[j] = f2b(prew[k * 16 + t]);
    }
}

// 512 threads / 16 samples per block (1 sample per 32-lane group).
// __launch_bounds__(512,4): 128-VGPR cap so the ~60-reg attention working set
// (xv[23] + masks + softmax state) stays in registers — (512,8)'s 64-reg cap
// forced 32+spill (R10/R11: WRITE_SIZE 55 MB of scratch, VALUBusy<40%).
// Attention: ballot row-mask + lane-local column softmax + row recompute.
// fc1: MFMA 16x16x32, wave w owns 16 cols, B from L2-hot ws. xc stored via
// f32 LDS tile -> one linear float4 per thread.
__global__ __launch_bounds__(BLK, 4) void gat_fused(
    const float* __restrict__ xattr, const int* __restrict__ adj,
    const float* __restrict__ W0,   const float* __restrict__ a0,
    const float* __restrict__ W1,   const float* __restrict__ a1,
    const unsigned short* __restrict__ w1t, const float* __restrict__ fc1b,
    const unsigned short* __restrict__ pwt, const float* __restrict__ preb,
    const float* __restrict__ predw, const float* __restrict__ predb,
    const float* __restrict__ varw,  const float* __restrict__ varb,
    float* __restrict__ outy, float* __restrict__ outv, float* __restrict__ outxc)
{
    __shared__ unsigned short s_feat[SPB * WST]; // 3328 B
    __shared__ unsigned short s_xc[SPB * XST];   // 4352 B
    __shared__ float s_xcf[SPB * FST];           // 8448 B
    __shared__ float s_fc1b[128];                // 512 B
    __shared__ float s_aux[64];                  // 256 B  -> ~16.9 KB total

    const int tid = threadIdx.x;

    if (tid < 128) s_fc1b[tid] = fc1b[tid];
    else if (tid < 144) {
        const int t = tid - 128;
        s_aux[12 + t] = preb[t];
        s_aux[28 + t] = predw[t];
        s_aux[44 + t] = varw[t];
    }
    else if (tid == 144) {
        s_aux[0] = W0[0]; s_aux[1] = W0[1];
        s_aux[2] = a0[0]; s_aux[3] = a0[1]; s_aux[4] = a0[2]; s_aux[5] = a0[3];
        s_aux[6] = W1[0]; s_aux[7] = W1[1];
        s_aux[8] = a1[0]; s_aux[9] = a1[1]; s_aux[10] = a1[2]; s_aux[11] = a1[3];
        s_aux[60] = predb[0]; s_aux[61] = varb[0];
    }
    else if (tid >= 160 && tid < 192) {          // zero s_feat pad cols 92..95
        const int r = (tid - 160) >> 1, u = tid & 1;
        *(unsigned*)&s_feat[r * WST + 92 + 2 * u] = 0u;
    }
    __syncthreads();

    const int group = tid >> 5;                  // 0..15 = local sample
    const int l     = tid & 31;
    const int s     = blockIdx.x * SPB + group;

    // ---- attention (1 sample per group) ----
    {
        float xl = 0.0f;
        if (l < NN) xl = xattr[s * NN + l];
        float xv[NN];
        #pragma unroll
        for (int i = 0; i < NN; ++i) xv[i] = __shfl(xl, i, 32);

        unsigned cm = 0u;
        if (l < NN) {
            const int* ar = adj + (size_t)s * (NN * NN);
            #pragma unroll
            for (int i = 0; i < NN; ++i) cm |= (ar[i * NN + l] != 0) ? (1u << i) : 0u;
        }
        unsigned rm = 0u;
        #pragma unroll
        for (int i = 0; i < NN; ++i) {
            unsigned long long bal = __ballot((cm >> i) & 1u);
            unsigned half = (unsigned)(bal >> (tid & 32));
            rm = (l == i) ? half : rm;
        }
        unsigned em;
        {
            unsigned long long bal = __ballot(cm == 0u);
            em = ((unsigned)(bal >> (tid & 32))) & 0x7FFFFFu;
        }
        float sbase = 0.0f;
        #pragma unroll
        for (int j = 0; j < NN; ++j) sbase += ((em >> j) & 1u) ? xv[j] : 0.0f;
        sbase *= (1.0f / 23.0f);   // jax softmax of all -1e20 -> uniform 1/23

        float fmine[4];
        #pragma unroll
        for (int h = 0; h < 2; ++h) {
            const float w0 = s_aux[h * 6 + 0], w1 = s_aux[h * 6 + 1];
            const float c1 = w0 * s_aux[h * 6 + 2] + w1 * s_aux[h * 6 + 3];
            const float c2 = w0 * s_aux[h * 6 + 4] + w1 * s_aux[h * 6 + 5];

            // column pass: dcol = sum_i masked exp(lrelu(c1*x_i + c2*x_l)) (lane-local)
            const float f2l = xl * c2;
            float dcol = 0.0f;
            #pragma unroll
            for (int i = 0; i < NN; ++i) {
                float e = fmaf(xv[i], c1, f2l);
                e = fmaxf(e, 0.2f * e);
                float t = ((cm >> i) & 1u) ? 1.0f : 0.0f;
                dcol = fmaf(__expf(e), t, dcol);
            }
            const float scl = (cm == 0u) ? 0.0f : __fdividef(xl, dcol);

            // row pass with inline broadcast
            const float f1 = xl * c1;
            float sown = sbase;
            #pragma unroll
            for (int j = 0; j < NN; ++j) {
                const float sj = __shfl(scl, j, 32);
                float e = fmaf(xv[j], c2, f1);
                e = fmaxf(e, 0.2f * e);
                sown = fmaf(__expf(e), ((rm >> j) & 1u) ? sj : 0.0f, sown);
            }
            fmine[h * 2 + 0] = geluf(w0 * sown);
            fmine[h * 2 + 1] = geluf(w1 * sown);
        }

        if (l < NN) {
            unsigned lo = (unsigned)f2b(fmine[0]) | ((unsigned)f2b(fmine[1]) << 16);
            unsigned hi = (unsigned)f2b(fmine[2]) | ((unsigned)f2b(fmine[3]) << 16);
            *(uint2*)&s_feat[group * WST + 4 * l] = make_uint2(lo, hi);
        }
    }
    __syncthreads();

    // ---- fc1 via MFMA: wave w (0..7) owns output cols [16w, 16w+16) ----
    {
        const int wave = tid >> 6;
        const int lane = tid & 63;
        const int q    = lane >> 4;      // k-chunk / C row-group
        const int c16  = lane & 15;
        const int n0   = 16 * wave + c16;

        f32x4 acc = {0.f, 0.f, 0.f, 0.f};
        #pragma unroll
        for (int t = 0; t < 3; ++t) {
            const bf16x8 a = *(const bf16x8*)&s_feat[c16 * WST + 32 * t + 8 * q];
            const bf16x8 b = *(const bf16x8*)&w1t[n0 * W1TK + 32 * t + 8 * q];
            acc = __builtin_amdgcn_mfma_f32_16x16x32_bf16(a, b, acc, 0, 0, 0);
        }
        const float bia = s_fc1b[n0];
        #pragma unroll
        for (int r = 0; r < 4; ++r) {
            const int srow = 4 * q + r;
            const float v = fmaxf(acc[r] + bia, 0.0f);
            s_xcf[srow * FST + n0] = v;
            s_xc[srow * XST + n0]  = f2b(v);
        }
    }
    __syncthreads();

    // ---- coalesced xc store: 512 threads x one linear float4 (8 KB/block) ----
    {
        const size_t gbase = (size_t)blockIdx.x * SPB * 128;
        const int row = tid >> 5, c = (tid & 31) * 4;
        *(float4*)&outxc[gbase + 4 * (size_t)tid] = *(const float4*)&s_xcf[row * FST + c];
    }

    // ---- pre via MFMA (wave 0, B from global) + epilogue ----
    if (tid < 64) {
        const int q   = tid >> 4;
        const int c16 = tid & 15;   // pre-output index
        f32x4 acc = {0.f, 0.f, 0.f, 0.f};
        #pragma unroll
        for (int t = 0; t < 4; ++t) {
            const bf16x8 a = *(const bf16x8*)&s_xc[c16 * XST + 32 * t + 8 * q];
            const bf16x8 b = *(const bf16x8*)&pwt[c16 * PWTK + 32 * t + 8 * q];
            acc = __builtin_amdgcn_mfma_f32_16x16x32_bf16(a, b, acc, 0, 0, 0);
        }
        const float pb = s_aux[12 + c16], pw = s_aux[28 + c16], vw = s_aux[44 + c16];
        float yp[4], vp[4];
        #pragma unroll
        for (int r = 0; r < 4; ++r) {
            const float g = geluf(acc[r] + pb);
            yp[r] = g * pw;
            vp[r] = g * vw;
        }
        #pragma unroll
        for (int m = 1; m < 16; m <<= 1) {
            #pragma unroll
            for (int r = 0; r < 4; ++r) {
                yp[r] += __shfl_xor(yp[r], m, 64);
                vp[r] += __shfl_xor(vp[r], m, 64);
            }
        }
        if (c16 == 0) {
            const int sb = blockIdx.x * SPB + 4 * q;
            #pragma unroll
            for (int r = 0; r < 4; ++r) {
                outy[sb + r] = fmaxf(yp[r] + s_aux[60], 0.0f);
                outv[sb + r] = vp[r] + s_aux[61];
            }
        }
    }
}

extern "C" void kernel_launch(void* const* d_in, const int* in_sizes, int n_in,
                              void* d_out, int out_size, void* d_ws, size_t ws_size,
                              hipStream_t stream) {
    const float* xattr = (const float*)d_in[0];
    const int*   adjp  = (const int*)d_in[1];

    const int B = in_sizes[0] / NN;   // 16384
    float* o = (float*)d_out;
    float* outy  = o;
    float* outv  = o + B;
    float* outxc = o + 2 * (size_t)B;

    unsigned short* w1t = (unsigned short*)d_ws;                  // 128*96*2 = 24576 B
    unsigned short* pwt = (unsigned short*)((char*)d_ws + 24576); // 16*128*2 =  4096 B

    prep<<<dim3(16), dim3(256), 0, stream>>>(
        (const float*)d_in[6], (const float*)d_in[8], w1t, pwt);

    gat_fused<<<dim3(B / SPB), dim3(BLK), 0, stream>>>(
        xattr, adjp,
        (const float*)d_in[2], (const float*)d_in[3],
        (const float*)d_in[4], (const float*)d_in[5],
        w1t, (const float*)d_in[7],
        pwt, (const float*)d_in[9],
        (const float*)d_in[10], (const float*)d_in[11],
        (const float*)d_in[12], (const float*)d_in[13],
        outy, outv, outxc);
}